// Round 3
// baseline (201.341 us; speedup 1.0000x reference)
//
#include <hip/hip_runtime.h>

typedef __bf16 bf16;
typedef __bf16 bf16x4 __attribute__((ext_vector_type(4)));
typedef __bf16 bf16x8 __attribute__((ext_vector_type(8)));
typedef float f32x4 __attribute__((ext_vector_type(4)));

#define S_LEN 2048
#define D_DIM 1024
#define N_HEAD 16
#define HEAD_DIM 64
#define M_TOK 4096
#define BH 32

#define EXP2F(x) __builtin_amdgcn_exp2f(x)
// 1/sqrt(64) * log2(e)
#define Q_SCALE 0.18033688f

typedef __attribute__((address_space(3))) void lds_void;
typedef const __attribute__((address_space(1))) void gbl_void;

__device__ __forceinline__ void gl_lds16(const bf16* g, bf16* l) {
  __builtin_amdgcn_global_load_lds((gbl_void*)g, (lds_void*)l, 16, 0, 0);
}

// ---------------- cast fp32 -> bf16 ----------------
__global__ __launch_bounds__(256) void k_cast(const float* __restrict__ x,
                                              bf16* __restrict__ o, int n) {
  int i = (blockIdx.x * 256 + threadIdx.x) * 4;
  if (i >= n) return;
  float4 v = *(const float4*)(x + i);
  bf16x4 w;
  w[0] = (bf16)v.x; w[1] = (bf16)v.y; w[2] = (bf16)v.z; w[3] = (bf16)v.w;
  *(bf16x4*)(o + i) = w;
}

// ---------------- transpose+cast: W[K][N] fp32 -> Wt[N][K] bf16 ----------------
__global__ __launch_bounds__(256) void k_transpose(const float* __restrict__ W,
                                                   bf16* __restrict__ Wt,
                                                   int K, int N) {
  __shared__ float tile[32][33];
  int nb = blockIdx.x, kb = blockIdx.y;
  int t = threadIdx.x;
  int r = t >> 3, c4 = (t & 7) * 4;
  float4 v = *(const float4*)&W[(kb * 32 + r) * N + nb * 32 + c4];
  tile[r][c4 + 0] = v.x; tile[r][c4 + 1] = v.y;
  tile[r][c4 + 2] = v.z; tile[r][c4 + 3] = v.w;
  __syncthreads();
  bf16x4 o;
  #pragma unroll
  for (int i = 0; i < 4; i++) o[i] = (bf16)tile[c4 + i][r];
  *(bf16x4*)&Wt[(nb * 32 + r) * K + kb * 32 + c4] = o;
}

// ---------------- GEMM1: qkv = x @ W_attn + b_attn ----------------
__global__ __launch_bounds__(256, 2)
void k_gemm_qkv(const bf16* __restrict__ A, const bf16* __restrict__ Bt,
                const float* __restrict__ bias,
                bf16* __restrict__ qk, bf16* __restrict__ vT) {
  __shared__ bf16 As[128 * 32];
  __shared__ bf16 Bs[128 * 32];
  const int K = 1024;
  int bn = blockIdx.x, bm = blockIdx.y;
  int t = threadIdx.x;
  int wave = t >> 6, lane = t & 63, c = lane & 15, quad = lane >> 4;
  int wm = wave & 1, wn = wave >> 1;
  int ldrow = lane >> 2, ldcol = (lane & 3) * 8;

  const bf16* Ag = A + (size_t)(bm * 128) * K;
  const bf16* Bg = Bt + (size_t)(bn * 128) * K;

  f32x4 acc[4][4] = {};

  for (int k0 = 0; k0 < K; k0 += 32) {
    __syncthreads();
    #pragma unroll
    for (int q = 0; q < 2; q++) {
      int r0 = (wave * 2 + q) * 16;
      gl_lds16(&Ag[(size_t)(r0 + ldrow) * K + k0 + ldcol], &As[r0 * 32]);
      gl_lds16(&Bg[(size_t)(r0 + ldrow) * K + k0 + ldcol], &Bs[r0 * 32]);
    }
    __syncthreads();
    bf16x8 af[4];
    #pragma unroll
    for (int mt = 0; mt < 4; mt++)
      af[mt] = *(const bf16x8*)&As[(wm * 64 + mt * 16 + c) * 32 + quad * 8];
    #pragma unroll
    for (int nt = 0; nt < 4; nt++) {
      bf16x8 bfr = *(const bf16x8*)&Bs[(wn * 64 + nt * 16 + c) * 32 + quad * 8];
      #pragma unroll
      for (int mt = 0; mt < 4; mt++)
        acc[mt][nt] = __builtin_amdgcn_mfma_f32_16x16x32_bf16(af[mt], bfr, acc[mt][nt], 0, 0, 0);
    }
  }

  #pragma unroll
  for (int nt = 0; nt < 4; nt++) {
    int n = bn * 128 + wn * 64 + nt * 16 + c;
    int which = n >> 10, nl = n & 1023;
    int h = nl >> 6, hd = nl & 63;
    float bv = bias[n];
    #pragma unroll
    for (int mt = 0; mt < 4; mt++) {
      int m0 = bm * 128 + wm * 64 + mt * 16 + quad * 4;
      int b = m0 >> 11, s0 = m0 & 2047;
      int bh = b * N_HEAD + h;
      if (which == 2) {
        bf16x4 o;
        #pragma unroll
        for (int r = 0; r < 4; r++) o[r] = (bf16)(acc[mt][nt][r] + bv);
        *(bf16x4*)&vT[((size_t)bh * HEAD_DIM + hd) * S_LEN + s0] = o;
      } else if (which == 0) {
        #pragma unroll
        for (int r = 0; r < 4; r++)
          qk[(bh * S_LEN + s0 + r) * HEAD_DIM + hd] = (bf16)((acc[mt][nt][r] + bv) * Q_SCALE);
      } else {
        #pragma unroll
        for (int r = 0; r < 4; r++)
          qk[BH * S_LEN * HEAD_DIM + (bh * S_LEN + s0 + r) * HEAD_DIM + hd] = (bf16)(acc[mt][nt][r] + bv);
      }
    }
  }
}

// ---------------- flash attention (causal), 128-row q-tiles, S^T/O^T layout ----------------
// grid 512: bh = bx&31, tile = 15 - (bx>>5) (largest tiles dispatch first).
// Wave w: strip A = rows tile*128 + w*16 .. +15, strip B = A + 64.
__global__ __launch_bounds__(256, 2)
void k_attn(const bf16* __restrict__ qk, const bf16* __restrict__ vT,
            bf16* __restrict__ y) {
  __shared__ bf16 Ks[64][72];    // [kpos][d]
  __shared__ bf16 Vs[64][72];    // [d][kpos]
  __shared__ bf16 Ps[128][72];   // [q][kpos], wave-private rows
  int bx = blockIdx.x;
  int bh = bx & 31;
  int tile = 15 - (bx >> 5);
  int t = threadIdx.x, w = t >> 6, lane = t & 63, c = lane & 15, quad = lane >> 4;
  const bf16* Qg = qk + (size_t)bh * (S_LEN * HEAD_DIM);
  const bf16* Kg = qk + (size_t)(BH + bh) * (S_LEN * HEAD_DIM);
  const bf16* Vg = vT + (size_t)bh * (HEAD_DIM * S_LEN);
  int b = bh >> 4, h = bh & 15;
  int srow = t >> 3, scol = (t & 7) * 8;

  int qA = tile * 128 + w * 16;
  int qB = qA + 64;
  int nkb = 2 * tile + 2;
  int dthr = w * 16 + c;   // local diag threshold for this lane's q-row

  bf16x8 qfA0 = *(const bf16x8*)&Qg[(qA + c) * HEAD_DIM + quad * 8];
  bf16x8 qfA1 = *(const bf16x8*)&Qg[(qA + c) * HEAD_DIM + 32 + quad * 8];
  bf16x8 qfB0 = *(const bf16x8*)&Qg[(qB + c) * HEAD_DIM + quad * 8];
  bf16x8 qfB1 = *(const bf16x8*)&Qg[(qB + c) * HEAD_DIM + 32 + quad * 8];

  float mA = -1e30f, lA = 0.f, mB = -1e30f, lB = 0.f;
  f32x4 accA[4] = {}, accB[4] = {};

  bf16x8 kr0 = *(const bf16x8*)&Kg[srow * HEAD_DIM + scol];
  bf16x8 kr1 = *(const bf16x8*)&Kg[(srow + 32) * HEAD_DIM + scol];
  bf16x8 vr0 = *(const bf16x8*)&Vg[(size_t)srow * S_LEN + scol];
  bf16x8 vr1 = *(const bf16x8*)&Vg[(size_t)(srow + 32) * S_LEN + scol];

  for (int kb = 0; kb < nkb; kb++) {
    __syncthreads();
    *(bf16x8*)&Ks[srow][scol] = kr0;
    *(bf16x8*)&Ks[srow + 32][scol] = kr1;
    *(bf16x8*)&Vs[srow][scol] = vr0;
    *(bf16x8*)&Vs[srow + 32][scol] = vr1;
    __syncthreads();
    if (kb + 1 < nkb) {
      kr0 = *(const bf16x8*)&Kg[((kb + 1) * 64 + srow) * HEAD_DIM + scol];
      kr1 = *(const bf16x8*)&Kg[((kb + 1) * 64 + srow + 32) * HEAD_DIM + scol];
      vr0 = *(const bf16x8*)&Vg[(size_t)srow * S_LEN + (kb + 1) * 64 + scol];
      vr1 = *(const bf16x8*)&Vg[(size_t)(srow + 32) * S_LEN + (kb + 1) * 64 + scol];
    }

    bool lastA = (kb == 2 * tile + 1);   // strip A fully masked: skip
    bool diagA = (kb == 2 * tile);
    bool diagB = (kb == 2 * tile + 1);

    // S^T = K Q^T : lane holds (kpos = kt*16+quad*4+r, q = c)
    f32x4 scA[4], scB[4];
    #pragma unroll
    for (int kt = 0; kt < 4; kt++) {
      bf16x8 kf0 = *(const bf16x8*)&Ks[kt * 16 + c][quad * 8];
      bf16x8 kf1 = *(const bf16x8*)&Ks[kt * 16 + c][32 + quad * 8];
      if (!lastA) {
        f32x4 z = {};
        z = __builtin_amdgcn_mfma_f32_16x16x32_bf16(kf0, qfA0, z, 0, 0, 0);
        z = __builtin_amdgcn_mfma_f32_16x16x32_bf16(kf1, qfA1, z, 0, 0, 0);
        scA[kt] = z;
      }
      f32x4 z = {};
      z = __builtin_amdgcn_mfma_f32_16x16x32_bf16(kf0, qfB0, z, 0, 0, 0);
      z = __builtin_amdgcn_mfma_f32_16x16x32_bf16(kf1, qfB1, z, 0, 0, 0);
      scB[kt] = z;
    }

    if (diagA) {
      #pragma unroll
      for (int kt = 0; kt < 4; kt++)
        #pragma unroll
        for (int r = 0; r < 4; r++)
          if (kt * 16 + quad * 4 + r > dthr) scA[kt][r] = -1e30f;
    }
    if (diagB) {
      #pragma unroll
      for (int kt = 0; kt < 4; kt++)
        #pragma unroll
        for (int r = 0; r < 4; r++)
          if (kt * 16 + quad * 4 + r > dthr) scB[kt][r] = -1e30f;
    }

    // softmax strip A
    if (!lastA) {
      float mx = scA[0][0];
      #pragma unroll
      for (int kt = 0; kt < 4; kt++)
        #pragma unroll
        for (int r = 0; r < 4; r++) mx = fmaxf(mx, scA[kt][r]);
      mx = fmaxf(mx, __shfl_xor(mx, 16));
      mx = fmaxf(mx, __shfl_xor(mx, 32));
      float mnew = fmaxf(mA, mx);
      float alpha = EXP2F(mA - mnew);
      float sum = 0.f;
      #pragma unroll
      for (int kt = 0; kt < 4; kt++) {
        bf16x4 pk;
        #pragma unroll
        for (int r = 0; r < 4; r++) {
          float pv = EXP2F(scA[kt][r] - mnew);
          sum += pv;
          pk[r] = (bf16)pv;
        }
        *(bf16x4*)&Ps[w * 16 + c][kt * 16 + quad * 4] = pk;
      }
      sum += __shfl_xor(sum, 16);
      sum += __shfl_xor(sum, 32);
      lA = lA * alpha + sum;
      mA = mnew;
      #pragma unroll
      for (int dt = 0; dt < 4; dt++)
        #pragma unroll
        for (int r = 0; r < 4; r++) accA[dt][r] *= alpha;
    }

    // softmax strip B
    {
      float mx = scB[0][0];
      #pragma unroll
      for (int kt = 0; kt < 4; kt++)
        #pragma unroll
        for (int r = 0; r < 4; r++) mx = fmaxf(mx, scB[kt][r]);
      mx = fmaxf(mx, __shfl_xor(mx, 16));
      mx = fmaxf(mx, __shfl_xor(mx, 32));
      float mnew = fmaxf(mB, mx);
      float alpha = EXP2F(mB - mnew);
      float sum = 0.f;
      #pragma unroll
      for (int kt = 0; kt < 4; kt++) {
        bf16x4 pk;
        #pragma unroll
        for (int r = 0; r < 4; r++) {
          float pv = EXP2F(scB[kt][r] - mnew);
          sum += pv;
          pk[r] = (bf16)pv;
        }
        *(bf16x4*)&Ps[64 + w * 16 + c][kt * 16 + quad * 4] = pk;
      }
      sum += __shfl_xor(sum, 16);
      sum += __shfl_xor(sum, 32);
      lB = lB * alpha + sum;
      mB = mnew;
      #pragma unroll
      for (int dt = 0; dt < 4; dt++)
        #pragma unroll
        for (int r = 0; r < 4; r++) accB[dt][r] *= alpha;
    }

    // O^T += V^T P^T  (A = Vs[d][kk], B = own wave's Ps rows)
    #pragma unroll
    for (int ks = 0; ks < 2; ks++) {
      bf16x8 pfB = *(const bf16x8*)&Ps[64 + w * 16 + c][ks * 32 + quad * 8];
      bf16x8 pfA;
      if (!lastA) pfA = *(const bf16x8*)&Ps[w * 16 + c][ks * 32 + quad * 8];
      #pragma unroll
      for (int dt = 0; dt < 4; dt++) {
        bf16x8 vf = *(const bf16x8*)&Vs[dt * 16 + c][ks * 32 + quad * 8];
        if (!lastA)
          accA[dt] = __builtin_amdgcn_mfma_f32_16x16x32_bf16(vf, pfA, accA[dt], 0, 0, 0);
        accB[dt] = __builtin_amdgcn_mfma_f32_16x16x32_bf16(vf, pfB, accB[dt], 0, 0, 0);
      }
    }
  }

  float liA = 1.0f / lA, liB = 1.0f / lB;
  #pragma unroll
  for (int dt = 0; dt < 4; dt++) {
    bf16x4 oA, oB;
    #pragma unroll
    for (int r = 0; r < 4; r++) {
      oA[r] = (bf16)(accA[dt][r] * liA);
      oB[r] = (bf16)(accB[dt][r] * liB);
    }
    *(bf16x4*)&y[((size_t)(b * S_LEN + qA + c) * N_HEAD + h) * HEAD_DIM + dt * 16 + quad * 4] = oA;
    *(bf16x4*)&y[((size_t)(b * S_LEN + qB + c) * N_HEAD + h) * HEAD_DIM + dt * 16 + quad * 4] = oB;
  }
}

// ---------------- GEMM2: out = y @ W_proj + b_proj, 128x64 tiles ----------------
__global__ __launch_bounds__(256, 2)
void k_gemm_proj(const bf16* __restrict__ A, const bf16* __restrict__ Bt,
                 const float* __restrict__ bias, float* __restrict__ out) {
  __shared__ bf16 As[128 * 32];
  __shared__ bf16 Bs[64 * 32];
  const int K = 1024;
  int bn = blockIdx.x, bm = blockIdx.y;
  int t = threadIdx.x;
  int wave = t >> 6, lane = t & 63, c = lane & 15, quad = lane >> 4;
  int wm = wave & 1, wn = wave >> 1;
  int ldrow = lane >> 2, ldcol = (lane & 3) * 8;

  const bf16* Ag = A + (size_t)(bm * 128) * K;
  const bf16* Bg = Bt + (size_t)(bn * 64) * K;

  f32x4 acc[4][2] = {};

  for (int k0 = 0; k0 < K; k0 += 32) {
    __syncthreads();
    #pragma unroll
    for (int q = 0; q < 2; q++) {
      int r0 = (wave * 2 + q) * 16;
      gl_lds16(&Ag[(size_t)(r0 + ldrow) * K + k0 + ldcol], &As[r0 * 32]);
    }
    gl_lds16(&Bg[(size_t)(wave * 16 + ldrow) * K + k0 + ldcol], &Bs[wave * 16 * 32]);
    __syncthreads();
    bf16x8 af[4];
    #pragma unroll
    for (int mt = 0; mt < 4; mt++)
      af[mt] = *(const bf16x8*)&As[(wm * 64 + mt * 16 + c) * 32 + quad * 8];
    #pragma unroll
    for (int nt = 0; nt < 2; nt++) {
      bf16x8 bfr = *(const bf16x8*)&Bs[(wn * 32 + nt * 16 + c) * 32 + quad * 8];
      #pragma unroll
      for (int mt = 0; mt < 4; mt++)
        acc[mt][nt] = __builtin_amdgcn_mfma_f32_16x16x32_bf16(af[mt], bfr, acc[mt][nt], 0, 0, 0);
    }
  }

  #pragma unroll
  for (int nt = 0; nt < 2; nt++) {
    int n = bn * 64 + wn * 32 + nt * 16 + c;
    float bv = bias[n];
    #pragma unroll
    for (int mt = 0; mt < 4; mt++) {
      #pragma unroll
      for (int r = 0; r < 4; r++) {
        int m = bm * 128 + wm * 64 + mt * 16 + quad * 4 + r;
        out[(size_t)m * D_DIM + n] = acc[mt][nt][r] + bv;
      }
    }
  }
}

extern "C" void kernel_launch(void* const* d_in, const int* in_sizes, int n_in,
                              void* d_out, int out_size, void* d_ws, size_t ws_size,
                              hipStream_t stream) {
  const float* x      = (const float*)d_in[0];
  const float* W_attn = (const float*)d_in[1];
  const float* b_attn = (const float*)d_in[2];
  const float* W_proj = (const float*)d_in[3];
  const float* b_proj = (const float*)d_in[4];
  float* out = (float*)d_out;

  bf16* x_bf = (bf16*)d_ws;
  bf16* wat  = x_bf + 4096 * 1024;
  bf16* wpt  = wat + 3072 * 1024;
  bf16* qk   = wpt + 1024 * 1024;
  bf16* vT   = qk + 8 * 1024 * 1024;
  bf16* y_bf = vT + 4 * 1024 * 1024;

  k_cast<<<4096, 256, 0, stream>>>(x, x_bf, 4096 * 1024);
  k_transpose<<<dim3(3072 / 32, 1024 / 32), 256, 0, stream>>>(W_attn, wat, 1024, 3072);
  k_transpose<<<dim3(1024 / 32, 1024 / 32), 256, 0, stream>>>(W_proj, wpt, 1024, 1024);
  k_gemm_qkv<<<dim3(24, 32), 256, 0, stream>>>(x_bf, wat, b_attn, qk, vT);
  k_attn<<<512, 256, 0, stream>>>(qk, vT, y_bf);
  k_gemm_proj<<<dim3(16, 32), 256, 0, stream>>>(y_bf, wpt, b_proj, out);
}

// Round 4
// 189.387 us; speedup vs baseline: 1.0631x; 1.0631x over previous
//
#include <hip/hip_runtime.h>

typedef __bf16 bf16;
typedef __bf16 bf16x4 __attribute__((ext_vector_type(4)));
typedef __bf16 bf16x8 __attribute__((ext_vector_type(8)));
typedef float f32x4 __attribute__((ext_vector_type(4)));

#define S_LEN 2048
#define D_DIM 1024
#define N_HEAD 16
#define HEAD_DIM 64
#define M_TOK 4096
#define BH 32

#define EXP2F(x) __builtin_amdgcn_exp2f(x)
// 1/sqrt(64) * log2(e)
#define Q_SCALE 0.18033688f

// LDS bank swizzle: conflict-free for our b64/b128 access patterns (stride 64, no pad)
#define SW(r, c) ((c) ^ (((r) & 3) << 4))

typedef __attribute__((address_space(3))) void lds_void;
typedef const __attribute__((address_space(1))) void gbl_void;

__device__ __forceinline__ void gl_lds16(const bf16* g, bf16* l) {
  __builtin_amdgcn_global_load_lds((gbl_void*)g, (lds_void*)l, 16, 0, 0);
}

// ---------------- cast fp32 -> bf16 ----------------
__global__ __launch_bounds__(256) void k_cast(const float* __restrict__ x,
                                              bf16* __restrict__ o, int n) {
  int i = (blockIdx.x * 256 + threadIdx.x) * 4;
  if (i >= n) return;
  float4 v = *(const float4*)(x + i);
  bf16x4 w;
  w[0] = (bf16)v.x; w[1] = (bf16)v.y; w[2] = (bf16)v.z; w[3] = (bf16)v.w;
  *(bf16x4*)(o + i) = w;
}

// ---------------- transpose+cast: W[K][N] fp32 -> Wt[N][K] bf16 ----------------
__global__ __launch_bounds__(256) void k_transpose(const float* __restrict__ W,
                                                   bf16* __restrict__ Wt,
                                                   int K, int N) {
  __shared__ float tile[32][33];
  int nb = blockIdx.x, kb = blockIdx.y;
  int t = threadIdx.x;
  int r = t >> 3, c4 = (t & 7) * 4;
  float4 v = *(const float4*)&W[(kb * 32 + r) * N + nb * 32 + c4];
  tile[r][c4 + 0] = v.x; tile[r][c4 + 1] = v.y;
  tile[r][c4 + 2] = v.z; tile[r][c4 + 3] = v.w;
  __syncthreads();
  bf16x4 o;
  #pragma unroll
  for (int i = 0; i < 4; i++) o[i] = (bf16)tile[c4 + i][r];
  *(bf16x4*)&Wt[(nb * 32 + r) * K + kb * 32 + c4] = o;
}

// ---------------- GEMM1: qkv = x @ W_attn + b_attn ----------------
__global__ __launch_bounds__(256, 2)
void k_gemm_qkv(const bf16* __restrict__ A, const bf16* __restrict__ Bt,
                const float* __restrict__ bias,
                bf16* __restrict__ qk, bf16* __restrict__ vT) {
  __shared__ bf16 As[128 * 32];
  __shared__ bf16 Bs[128 * 32];
  const int K = 1024;
  int bn = blockIdx.x, bm = blockIdx.y;
  int t = threadIdx.x;
  int wave = t >> 6, lane = t & 63, c = lane & 15, quad = lane >> 4;
  int wm = wave & 1, wn = wave >> 1;
  int ldrow = lane >> 2, ldcol = (lane & 3) * 8;

  const bf16* Ag = A + (size_t)(bm * 128) * K;
  const bf16* Bg = Bt + (size_t)(bn * 128) * K;

  f32x4 acc[4][4] = {};

  for (int k0 = 0; k0 < K; k0 += 32) {
    __syncthreads();
    #pragma unroll
    for (int q = 0; q < 2; q++) {
      int r0 = (wave * 2 + q) * 16;
      gl_lds16(&Ag[(size_t)(r0 + ldrow) * K + k0 + ldcol], &As[r0 * 32]);
      gl_lds16(&Bg[(size_t)(r0 + ldrow) * K + k0 + ldcol], &Bs[r0 * 32]);
    }
    __syncthreads();
    bf16x8 af[4];
    #pragma unroll
    for (int mt = 0; mt < 4; mt++)
      af[mt] = *(const bf16x8*)&As[(wm * 64 + mt * 16 + c) * 32 + quad * 8];
    #pragma unroll
    for (int nt = 0; nt < 4; nt++) {
      bf16x8 bfr = *(const bf16x8*)&Bs[(wn * 64 + nt * 16 + c) * 32 + quad * 8];
      #pragma unroll
      for (int mt = 0; mt < 4; mt++)
        acc[mt][nt] = __builtin_amdgcn_mfma_f32_16x16x32_bf16(af[mt], bfr, acc[mt][nt], 0, 0, 0);
    }
  }

  #pragma unroll
  for (int nt = 0; nt < 4; nt++) {
    int n = bn * 128 + wn * 64 + nt * 16 + c;
    int which = n >> 10, nl = n & 1023;
    int h = nl >> 6, hd = nl & 63;
    float bv = bias[n];
    #pragma unroll
    for (int mt = 0; mt < 4; mt++) {
      int m0 = bm * 128 + wm * 64 + mt * 16 + quad * 4;
      int b = m0 >> 11, s0 = m0 & 2047;
      int bh = b * N_HEAD + h;
      if (which == 2) {
        bf16x4 o;
        #pragma unroll
        for (int r = 0; r < 4; r++) o[r] = (bf16)(acc[mt][nt][r] + bv);
        *(bf16x4*)&vT[((size_t)bh * HEAD_DIM + hd) * S_LEN + s0] = o;
      } else if (which == 0) {
        #pragma unroll
        for (int r = 0; r < 4; r++)
          qk[(bh * S_LEN + s0 + r) * HEAD_DIM + hd] = (bf16)((acc[mt][nt][r] + bv) * Q_SCALE);
      } else {
        #pragma unroll
        for (int r = 0; r < 4; r++)
          qk[BH * S_LEN * HEAD_DIM + (bh * S_LEN + s0 + r) * HEAD_DIM + hd] = (bf16)(acc[mt][nt][r] + bv);
      }
    }
  }
}

// ---------------- flash attention (causal), merged-pair K-loop ----------------
// grid 512: bh = bx&31, pair p = bx>>5 (0..15). Block handles 64-row q-tiles
// {p, 31-p} in ONE kb loop (kb = 0..31-p). Strip A (tile p) active while
// kb <= p; both strips share staged K/V + kf/vf reads. Uniform 33 work-units.
// LDS: XOR-swizzled (SW), double-buffered K/V (one barrier per iter).
__global__ __launch_bounds__(256, 2)
void k_attn(const bf16* __restrict__ qk, const bf16* __restrict__ vT,
            bf16* __restrict__ y) {
  __shared__ bf16 Ks[2][64][64];   // [buf][kpos][d]  (swizzled cols)
  __shared__ bf16 Vs[2][64][64];   // [buf][d][kpos]
  __shared__ bf16 Ps[128][64];     // [strip*64 + q][kpos], wave-private rows
  int bx = blockIdx.x;
  int bh = bx & 31;
  int p = bx >> 5;
  int t = threadIdx.x, w = t >> 6, lane = t & 63, c = lane & 15, quad = lane >> 4;
  const bf16* Qg = qk + (size_t)bh * (S_LEN * HEAD_DIM);
  const bf16* Kg = qk + (size_t)(BH + bh) * (S_LEN * HEAD_DIM);
  const bf16* Vg = vT + (size_t)bh * (HEAD_DIM * S_LEN);
  int b = bh >> 4, h = bh & 15;
  int srow = t >> 3, scol = (t & 7) * 8;
  int swcol = SW(srow, scol);      // same for srow and srow+32

  const int tileQ0 = p, tileQ1 = 31 - p;
  const int nkb = 32 - p;
  const int dthr = w * 16 + c;

  bf16x8 qf[2][2];
  f32x4 acc[2][4] = {};
  float mM[2] = {-1e30f, -1e30f}, lL[2] = {0.f, 0.f};
  {
    int qr0 = tileQ0 * 64 + w * 16 + c;
    int qr1 = tileQ1 * 64 + w * 16 + c;
    qf[0][0] = *(const bf16x8*)&Qg[qr0 * HEAD_DIM + quad * 8];
    qf[0][1] = *(const bf16x8*)&Qg[qr0 * HEAD_DIM + 32 + quad * 8];
    qf[1][0] = *(const bf16x8*)&Qg[qr1 * HEAD_DIM + quad * 8];
    qf[1][1] = *(const bf16x8*)&Qg[qr1 * HEAD_DIM + 32 + quad * 8];
  }

  // prologue: prefetch + stage kb=0 into buf 0
  bf16x8 kr0 = *(const bf16x8*)&Kg[srow * HEAD_DIM + scol];
  bf16x8 kr1 = *(const bf16x8*)&Kg[(srow + 32) * HEAD_DIM + scol];
  bf16x8 vr0 = *(const bf16x8*)&Vg[(size_t)srow * S_LEN + scol];
  bf16x8 vr1 = *(const bf16x8*)&Vg[(size_t)(srow + 32) * S_LEN + scol];
  *(bf16x8*)&Ks[0][srow][swcol] = kr0;
  *(bf16x8*)&Ks[0][srow + 32][swcol] = kr1;
  *(bf16x8*)&Vs[0][srow][swcol] = vr0;
  *(bf16x8*)&Vs[0][srow + 32][swcol] = vr1;

  for (int kb = 0; kb < nkb; kb++) {
    __syncthreads();   // buf[kb&1] visible; licenses writing buf[(kb+1)&1]
    int cur = kb & 1;
    bool haveNext = (kb + 1 < nkb);
    if (haveNext) {
      kr0 = *(const bf16x8*)&Kg[((kb + 1) * 64 + srow) * HEAD_DIM + scol];
      kr1 = *(const bf16x8*)&Kg[((kb + 1) * 64 + srow + 32) * HEAD_DIM + scol];
      vr0 = *(const bf16x8*)&Vg[(size_t)srow * S_LEN + (kb + 1) * 64 + scol];
      vr1 = *(const bf16x8*)&Vg[(size_t)(srow + 32) * S_LEN + (kb + 1) * 64 + scol];
    }

    bool act0 = (kb <= p);
    bool dia0 = (kb == p);
    bool dia1 = (kb == 31 - p);

    // S^T = K Q^T : lane holds (kpos = kt*16+quad*4+r, q = c)
    f32x4 sc[2][4];
    #pragma unroll
    for (int kt = 0; kt < 4; kt++) {
      int kr = kt * 16 + c;
      bf16x8 kf0 = *(const bf16x8*)&Ks[cur][kr][SW(kr, quad * 8)];
      bf16x8 kf1 = *(const bf16x8*)&Ks[cur][kr][SW(kr, 32 + quad * 8)];
      if (act0) {
        f32x4 z = {};
        z = __builtin_amdgcn_mfma_f32_16x16x32_bf16(kf0, qf[0][0], z, 0, 0, 0);
        z = __builtin_amdgcn_mfma_f32_16x16x32_bf16(kf1, qf[0][1], z, 0, 0, 0);
        sc[0][kt] = z;
      }
      f32x4 z = {};
      z = __builtin_amdgcn_mfma_f32_16x16x32_bf16(kf0, qf[1][0], z, 0, 0, 0);
      z = __builtin_amdgcn_mfma_f32_16x16x32_bf16(kf1, qf[1][1], z, 0, 0, 0);
      sc[1][kt] = z;
    }

    if (dia0) {
      #pragma unroll
      for (int kt = 0; kt < 4; kt++)
        #pragma unroll
        for (int r = 0; r < 4; r++)
          if (kt * 16 + quad * 4 + r > dthr) sc[0][kt][r] = -1e30f;
    }
    if (dia1) {
      #pragma unroll
      for (int kt = 0; kt < 4; kt++)
        #pragma unroll
        for (int r = 0; r < 4; r++)
          if (kt * 16 + quad * 4 + r > dthr) sc[1][kt][r] = -1e30f;
    }

    // online softmax per strip (lane's q-row = c); Ps rows are wave-private
    #pragma unroll
    for (int st = 0; st < 2; st++) {
      if (st == 0 && !act0) continue;
      float mx = sc[st][0][0];
      #pragma unroll
      for (int kt = 0; kt < 4; kt++)
        #pragma unroll
        for (int r = 0; r < 4; r++) mx = fmaxf(mx, sc[st][kt][r]);
      mx = fmaxf(mx, __shfl_xor(mx, 16));
      mx = fmaxf(mx, __shfl_xor(mx, 32));
      float mnew = fmaxf(mM[st], mx);
      float alpha = EXP2F(mM[st] - mnew);
      float sum = 0.f;
      int prow = st * 64 + w * 16 + c;
      #pragma unroll
      for (int kt = 0; kt < 4; kt++) {
        bf16x4 pk;
        #pragma unroll
        for (int r = 0; r < 4; r++) {
          float pv = EXP2F(sc[st][kt][r] - mnew);
          sum += pv;
          pk[r] = (bf16)pv;
        }
        *(bf16x4*)&Ps[prow][SW(prow, kt * 16 + quad * 4)] = pk;
      }
      sum += __shfl_xor(sum, 16);
      sum += __shfl_xor(sum, 32);
      lL[st] = lL[st] * alpha + sum;
      mM[st] = mnew;
      #pragma unroll
      for (int dt = 0; dt < 4; dt++)
        #pragma unroll
        for (int r = 0; r < 4; r++) acc[st][dt][r] *= alpha;
    }

    // O^T += V^T P^T
    #pragma unroll
    for (int ks = 0; ks < 2; ks++) {
      int prow1 = 64 + w * 16 + c;
      bf16x8 pf1 = *(const bf16x8*)&Ps[prow1][SW(prow1, ks * 32 + quad * 8)];
      bf16x8 pf0;
      if (act0) {
        int prow0 = w * 16 + c;
        pf0 = *(const bf16x8*)&Ps[prow0][SW(prow0, ks * 32 + quad * 8)];
      }
      #pragma unroll
      for (int dt = 0; dt < 4; dt++) {
        int vrow = dt * 16 + c;
        bf16x8 vf = *(const bf16x8*)&Vs[cur][vrow][SW(vrow, ks * 32 + quad * 8)];
        if (act0)
          acc[0][dt] = __builtin_amdgcn_mfma_f32_16x16x32_bf16(vf, pf0, acc[0][dt], 0, 0, 0);
        acc[1][dt] = __builtin_amdgcn_mfma_f32_16x16x32_bf16(vf, pf1, acc[1][dt], 0, 0, 0);
      }
    }

    // stage next block into the other buffer (safe: all waves passed this
    // iter's barrier, so nobody still reads buf[cur^1] from iter kb-1)
    if (haveNext) {
      int nxt = cur ^ 1;
      *(bf16x8*)&Ks[nxt][srow][swcol] = kr0;
      *(bf16x8*)&Ks[nxt][srow + 32][swcol] = kr1;
      *(bf16x8*)&Vs[nxt][srow][swcol] = vr0;
      *(bf16x8*)&Vs[nxt][srow + 32][swcol] = vr1;
    }
  }

  #pragma unroll
  for (int st = 0; st < 2; st++) {
    int q = (st == 0 ? tileQ0 : tileQ1) * 64 + w * 16 + c;
    float linv = 1.0f / lL[st];
    #pragma unroll
    for (int dt = 0; dt < 4; dt++) {
      bf16x4 o;
      #pragma unroll
      for (int r = 0; r < 4; r++) o[r] = (bf16)(acc[st][dt][r] * linv);
      *(bf16x4*)&y[((size_t)(b * S_LEN + q) * N_HEAD + h) * HEAD_DIM + dt * 16 + quad * 4] = o;
    }
  }
}

// ---------------- GEMM2: out = y @ W_proj + b_proj, 128x64 tiles ----------------
__global__ __launch_bounds__(256, 2)
void k_gemm_proj(const bf16* __restrict__ A, const bf16* __restrict__ Bt,
                 const float* __restrict__ bias, float* __restrict__ out) {
  __shared__ bf16 As[128 * 32];
  __shared__ bf16 Bs[64 * 32];
  const int K = 1024;
  int bn = blockIdx.x, bm = blockIdx.y;
  int t = threadIdx.x;
  int wave = t >> 6, lane = t & 63, c = lane & 15, quad = lane >> 4;
  int wm = wave & 1, wn = wave >> 1;
  int ldrow = lane >> 2, ldcol = (lane & 3) * 8;

  const bf16* Ag = A + (size_t)(bm * 128) * K;
  const bf16* Bg = Bt + (size_t)(bn * 64) * K;

  f32x4 acc[4][2] = {};

  for (int k0 = 0; k0 < K; k0 += 32) {
    __syncthreads();
    #pragma unroll
    for (int q = 0; q < 2; q++) {
      int r0 = (wave * 2 + q) * 16;
      gl_lds16(&Ag[(size_t)(r0 + ldrow) * K + k0 + ldcol], &As[r0 * 32]);
    }
    gl_lds16(&Bg[(size_t)(wave * 16 + ldrow) * K + k0 + ldcol], &Bs[wave * 16 * 32]);
    __syncthreads();
    bf16x8 af[4];
    #pragma unroll
    for (int mt = 0; mt < 4; mt++)
      af[mt] = *(const bf16x8*)&As[(wm * 64 + mt * 16 + c) * 32 + quad * 8];
    #pragma unroll
    for (int nt = 0; nt < 2; nt++) {
      bf16x8 bfr = *(const bf16x8*)&Bs[(wn * 32 + nt * 16 + c) * 32 + quad * 8];
      #pragma unroll
      for (int mt = 0; mt < 4; mt++)
        acc[mt][nt] = __builtin_amdgcn_mfma_f32_16x16x32_bf16(af[mt], bfr, acc[mt][nt], 0, 0, 0);
    }
  }

  #pragma unroll
  for (int nt = 0; nt < 2; nt++) {
    int n = bn * 64 + wn * 32 + nt * 16 + c;
    float bv = bias[n];
    #pragma unroll
    for (int mt = 0; mt < 4; mt++) {
      #pragma unroll
      for (int r = 0; r < 4; r++) {
        int m = bm * 128 + wm * 64 + mt * 16 + quad * 4 + r;
        out[(size_t)m * D_DIM + n] = acc[mt][nt][r] + bv;
      }
    }
  }
}

extern "C" void kernel_launch(void* const* d_in, const int* in_sizes, int n_in,
                              void* d_out, int out_size, void* d_ws, size_t ws_size,
                              hipStream_t stream) {
  const float* x      = (const float*)d_in[0];
  const float* W_attn = (const float*)d_in[1];
  const float* b_attn = (const float*)d_in[2];
  const float* W_proj = (const float*)d_in[3];
  const float* b_proj = (const float*)d_in[4];
  float* out = (float*)d_out;

  bf16* x_bf = (bf16*)d_ws;
  bf16* wat  = x_bf + 4096 * 1024;
  bf16* wpt  = wat + 3072 * 1024;
  bf16* qk   = wpt + 1024 * 1024;
  bf16* vT   = qk + 8 * 1024 * 1024;
  bf16* y_bf = vT + 4 * 1024 * 1024;

  k_cast<<<4096, 256, 0, stream>>>(x, x_bf, 4096 * 1024);
  k_transpose<<<dim3(3072 / 32, 1024 / 32), 256, 0, stream>>>(W_attn, wat, 1024, 3072);
  k_transpose<<<dim3(1024 / 32, 1024 / 32), 256, 0, stream>>>(W_proj, wpt, 1024, 1024);
  k_gemm_qkv<<<dim3(24, 32), 256, 0, stream>>>(x_bf, wat, b_attn, qk, vT);
  k_attn<<<512, 256, 0, stream>>>(qk, vT, y_bf);
  k_gemm_proj<<<dim3(16, 32), 256, 0, stream>>>(y_bf, wpt, b_proj, out);
}